// Round 3
// baseline (484.136 us; speedup 1.0000x reference)
//
#include <hip/hip_runtime.h>

// Problem constants (fixed by the reference)
#define NN 200000   // nodes
#define CC 256      // channels
#define NG 512      // graphs/segments

typedef __attribute__((ext_vector_type(8))) __bf16 bf16x8;
typedef __attribute__((ext_vector_type(4))) float f32x4;

__device__ __forceinline__ unsigned short f2bf(float f) {
  union { float f; unsigned u; } v; v.f = f;
  unsigned u = v.u;
  u += 0x7fffu + ((u >> 16) & 1u);   // RNE
  return (unsigned short)(u >> 16);
}
__device__ __forceinline__ unsigned pack2(float a, float b) {
  return (unsigned)f2bf(a) | ((unsigned)f2bf(b) << 16);
}
__device__ __forceinline__ float bflo(unsigned u){ union{unsigned u; float f;} x; x.u = u << 16; return x.f; }
__device__ __forceinline__ float bfhi(unsigned u){ union{unsigned u; float f;} x; x.u = u & 0xffff0000u; return x.f; }

// ---------------------------------------------------------------------------
// K0: prep weights into MFMA B-fragment order.
//  Layout: frag[slice*4096 + ks*512 + lane*8 + j] =
//          W[k = ks*32 + (lane>>4)*8 + j][col = (slice&15)*16 + (lane&15)]
//  Wfrag: 48 slices (V:0-15, Q:16-31, K:32-47).  Wo_frag: 16 slices.
// ---------------------------------------------------------------------------
__global__ __launch_bounds__(256) void prep_kernel(
    const float* __restrict__ Wq, const float* __restrict__ Wk,
    const float* __restrict__ Wv, const float* __restrict__ Wo,
    unsigned short* __restrict__ Wfrag, unsigned short* __restrict__ Wo_frag) {
  int idx = blockIdx.x * 256 + threadIdx.x;   // grid 1024*256 = 262144
  const float* W;
  unsigned short* dst;
  int rel;
  if (idx < 196608) {
    rel = idx;
    int m = rel >> 16;                        // 0=V,1=Q,2=K
    W = (m == 0) ? Wv : (m == 1) ? Wq : Wk;
    dst = Wfrag + rel;
  } else {
    rel = idx - 196608;
    W = Wo;
    dst = Wo_frag + rel;
  }
  int q = rel & 65535;
  int slice16 = q >> 12;                      // slice within matrix (0..15)
  int inner = q & 4095;
  int ks = inner >> 9;
  int lane = (inner >> 3) & 63;
  int j = inner & 7;
  int col = slice16 * 16 + (lane & 15);
  int k = ks * 32 + (lane >> 4) * 8 + j;
  *dst = f2bf(W[k * 256 + col]);
}

// ---------------------------------------------------------------------------
// K1: segment boundaries from sorted batch.
// ---------------------------------------------------------------------------
__global__ __launch_bounds__(256) void seg_bounds_kernel(
    const int* __restrict__ batch, int* __restrict__ seg_start, int n) {
  int i = blockIdx.x * 256 + threadIdx.x;
  if (i >= n) return;
  int a = batch[i];
  int b = (i + 1 < n) ? batch[i + 1] : NG;
  for (int g = a + 1; g <= b; ++g) seg_start[g] = i + 1;
  if (i == 0) for (int g = 0; g <= a; ++g) seg_start[g] = 0;
}

// ---------------------------------------------------------------------------
// one 16x16 output slice: full K=256 via 8 MFMAs, B-frags straight from L2.
// ---------------------------------------------------------------------------
__device__ __forceinline__ f32x4 gemm_slice(const bf16x8 afr[8],
    const unsigned short* __restrict__ W, int slice, int lane) {
  const unsigned short* wp = W + slice * 4096 + lane * 8;
  f32x4 acc = {0.f, 0.f, 0.f, 0.f};
#pragma unroll
  for (int ks = 0; ks < 8; ++ks) {
    bf16x8 bfr = *reinterpret_cast<const bf16x8*>(wp + ks * 512);
    acc = __builtin_amdgcn_mfma_f32_16x16x32_bf16(afr[ks], bfr, acc, 0, 0, 0);
  }
  return acc;
}

// ---------------------------------------------------------------------------
// K2: fused QKV GEMM + per-node scores.  ONE WAVE per 16 rows, zero barriers.
//  A-frags in regs; B from L2; V staged via 2.3KB wave-private LDS; Q packed
//  bf16 in regs; K chunks fold directly into the score dot (same-lane q,k) +
//  shfl_xor butterfly over the 16-lane row group.
// ---------------------------------------------------------------------------
__global__ __launch_bounds__(64, 4) void qkv_scores_kernel(
    const float* __restrict__ x, const unsigned short* __restrict__ Wfrag,
    const float* __restrict__ bq, const float* __restrict__ bk,
    const float* __restrict__ bv,
    unsigned short* __restrict__ v_out,   // [NN][256] bf16
    float* __restrict__ scores) {         // [NN][16]
  __shared__ unsigned short vstage[16 * 72];   // stride 72 shorts: 16B-aligned rows

  const int lane = threadIdx.x;
  const int lr = lane & 15, hi = lane >> 4;
  const int r0 = blockIdx.x * 16;

  // ---- A fragments: x rows r0..r0+15, fp32 -> bf16, straight to regs ----
  bf16x8 afr[8];
#pragma unroll
  for (int ks = 0; ks < 8; ++ks) {
    const float* px = x + (size_t)(r0 + lr) * CC + ks * 32 + hi * 8;
    float4 a0 = *reinterpret_cast<const float4*>(px);
    float4 a1 = *reinterpret_cast<const float4*>(px + 4);
    uint4 u = {pack2(a0.x, a0.y), pack2(a0.z, a0.w),
               pack2(a1.x, a1.y), pack2(a1.z, a1.w)};
    afr[ks] = *reinterpret_cast<bf16x8*>(&u);
  }

  // ---- V: 4 chunks -> wave-private LDS stage -> coalesced global bf16 ----
  for (int cg = 0; cg < 4; ++cg) {
#pragma unroll
    for (int s = 0; s < 4; ++s) {
      f32x4 acc = gemm_slice(afr, Wfrag, cg * 4 + s, lane);
      float bias = bv[cg * 64 + s * 16 + lr];
#pragma unroll
      for (int r = 0; r < 4; ++r)
        vstage[(hi * 4 + r) * 72 + s * 16 + lr] = f2bf(acc[r] + bias);
    }
    {   // wave-synchronous copy-out (compiler inserts lgkmcnt)
      int row = lane >> 2, q = lane & 3;
      uint4 d0 = *reinterpret_cast<const uint4*>(&vstage[row * 72 + q * 16]);
      uint4 d1 = *reinterpret_cast<const uint4*>(&vstage[row * 72 + q * 16 + 8]);
      unsigned short* vp = v_out + (size_t)(r0 + row) * CC + cg * 64 + q * 16;
      *reinterpret_cast<uint4*>(vp) = d0;
      *reinterpret_cast<uint4*>(vp + 8) = d1;
    }
  }

  // ---- Q: 4 heads, kept packed bf16 in registers ----
  unsigned qp[4][4][2];
#pragma unroll
  for (int h = 0; h < 4; ++h)
#pragma unroll
    for (int s = 0; s < 4; ++s) {
      f32x4 acc = gemm_slice(afr, Wfrag, (4 + h) * 4 + s, lane);
      float bias = bq[h * 64 + s * 16 + lr];
      qp[h][s][0] = pack2(acc[0] + bias, acc[1] + bias);
      qp[h][s][1] = pack2(acc[2] + bias, acc[3] + bias);
    }

  // ---- K: 4 heads; dot with q in-lane, butterfly over lr, store scores ----
  for (int g = 0; g < 4; ++g) {
    float sp[4][4];
#pragma unroll
    for (int h = 0; h < 4; ++h)
#pragma unroll
      for (int r = 0; r < 4; ++r) sp[h][r] = 0.f;

#pragma unroll
    for (int s = 0; s < 4; ++s) {
      f32x4 acc = gemm_slice(afr, Wfrag, (8 + g) * 4 + s, lane);
      float bias = bk[g * 64 + s * 16 + lr];
      float k0 = acc[0] + bias, k1 = acc[1] + bias;
      float k2 = acc[2] + bias, k3 = acc[3] + bias;
#pragma unroll
      for (int h = 0; h < 4; ++h) {
        sp[h][0] += bflo(qp[h][s][0]) * k0;
        sp[h][1] += bfhi(qp[h][s][0]) * k1;
        sp[h][2] += bflo(qp[h][s][1]) * k2;
        sp[h][3] += bfhi(qp[h][s][1]) * k3;
      }
    }
#pragma unroll
    for (int m = 1; m <= 8; m <<= 1)
#pragma unroll
      for (int h = 0; h < 4; ++h)
#pragma unroll
        for (int r = 0; r < 4; ++r)
          sp[h][r] += __shfl_xor(sp[h][r], m, 64);

#pragma unroll
    for (int r = 0; r < 4; ++r) {
      float v = (lr == 0) ? sp[0][r] : (lr == 1) ? sp[1][r]
              : (lr == 2) ? sp[2][r] : sp[3][r];
      if (lr < 4)
        scores[(size_t)(r0 + hi * 4 + r) * 16 + lr * 4 + g] = v * 0.125f;
    }
  }
}

// ---------------------------------------------------------------------------
// K3: per-segment max & exp-sum over the 16 score columns (block per segment).
// ---------------------------------------------------------------------------
__global__ __launch_bounds__(256) void seg_softmax_kernel(
    const float* __restrict__ scores, const int* __restrict__ seg_start,
    float* __restrict__ seg_max, float* __restrict__ seg_sum) {
  __shared__ float red[256];
  int g = blockIdx.x;
  int s = seg_start[g], e = seg_start[g + 1];
  int t = threadIdx.x;
  int col = t & 15, sub = t >> 4;

  float m = -INFINITY;
  for (int i = s + sub; i < e; i += 16)
    m = fmaxf(m, scores[(size_t)i * 16 + col]);
  red[t] = m;
  __syncthreads();
  for (int step = 8; step >= 1; step >>= 1) {
    if (sub < step) red[t] = fmaxf(red[t], red[t + step * 16]);
    __syncthreads();
  }
  if (t < 16) seg_max[g * 16 + t] = red[t];
  float mcol = red[col];
  __syncthreads();

  float sum = 0.f;
  for (int i = s + sub; i < e; i += 16)
    sum += expf(scores[(size_t)i * 16 + col] - mcol);
  red[t] = sum;
  __syncthreads();
  for (int step = 8; step >= 1; step >>= 1) {
    if (sub < step) red[t] += red[t + step * 16];
    __syncthreads();
  }
  if (t < 16) seg_sum[g * 16 + t] = red[t];
}

// ---------------------------------------------------------------------------
// K4: fused att + att.v + output GEMM (+bo) + att_mean.  ONE WAVE per 16
//     nodes, zero LDS, zero barriers.  out_attn built per-lane into A-frags.
// ---------------------------------------------------------------------------
__global__ __launch_bounds__(64, 4) void out_kernel(
    const unsigned short* __restrict__ v_bf, const float* __restrict__ scores,
    const int* __restrict__ batch, const float* __restrict__ seg_max,
    const float* __restrict__ seg_sum,
    const unsigned short* __restrict__ Wo_frag,
    const float* __restrict__ bo, float* __restrict__ out,
    float* __restrict__ att_mean) {
  const int lane = threadIdx.x;
  const int lr = lane & 15, hi = lane >> 4;
  const int r0 = blockIdx.x * 16;
  const int n = r0 + lr;

  // ---- att[16] for this lane's node ----
  int b = batch[n];
  float att[16];
#pragma unroll
  for (int q = 0; q < 4; ++q) {
    float4 sc = *reinterpret_cast<const float4*>(scores + (size_t)n * 16 + q * 4);
    float4 mx = *reinterpret_cast<const float4*>(seg_max + b * 16 + q * 4);
    float4 sm = *reinterpret_cast<const float4*>(seg_sum + b * 16 + q * 4);
    att[q * 4 + 0] = expf(sc.x - mx.x) / (sm.x + 1e-16f);
    att[q * 4 + 1] = expf(sc.y - mx.y) / (sm.y + 1e-16f);
    att[q * 4 + 2] = expf(sc.z - mx.z) / (sm.z + 1e-16f);
    att[q * 4 + 3] = expf(sc.w - mx.w) / (sm.w + 1e-16f);
  }
  if (hi == 0) {
    float4 am;
    am.x = 0.25f * (att[0] + att[4] + att[8] + att[12]);
    am.y = 0.25f * (att[1] + att[5] + att[9] + att[13]);
    am.z = 0.25f * (att[2] + att[6] + att[10] + att[14]);
    am.w = 0.25f * (att[3] + att[7] + att[11] + att[15]);
    *reinterpret_cast<float4*>(att_mean + (size_t)n * 4) = am;
  }

  // ---- v row (bf16, packed) ----
  uint4 vv[2][4];   // [w = upper/lower 32 of head][g]
#pragma unroll
  for (int g = 0; g < 4; ++g)
#pragma unroll
    for (int w = 0; w < 2; ++w)
      vv[w][g] = *reinterpret_cast<const uint4*>(
          v_bf + (size_t)n * CC + g * 64 + w * 32 + hi * 8);

  // ---- out_attn A-frags: frag[ks][j] = sum_g att[h][g] * v[g][d] ----
  bf16x8 afr[8];
#pragma unroll
  for (int ks = 0; ks < 8; ++ks) {
    const int h = ks >> 1, w = ks & 1;
    unsigned res[4];
#pragma unroll
    for (int j2 = 0; j2 < 4; ++j2) {
      unsigned u0 = ((const unsigned*)&vv[w][0])[j2];
      unsigned u1 = ((const unsigned*)&vv[w][1])[j2];
      unsigned u2 = ((const unsigned*)&vv[w][2])[j2];
      unsigned u3 = ((const unsigned*)&vv[w][3])[j2];
      float lo = att[h * 4 + 0] * bflo(u0) + att[h * 4 + 1] * bflo(u1) +
                 att[h * 4 + 2] * bflo(u2) + att[h * 4 + 3] * bflo(u3);
      float hf = att[h * 4 + 0] * bfhi(u0) + att[h * 4 + 1] * bfhi(u1) +
                 att[h * 4 + 2] * bfhi(u2) + att[h * 4 + 3] * bfhi(u3);
      res[j2] = pack2(lo, hf);
    }
    uint4 r4 = {res[0], res[1], res[2], res[3]};
    afr[ks] = *reinterpret_cast<bf16x8*>(&r4);
  }

  // ---- output GEMM: 16 slices of 16 cols ----
  for (int sl = 0; sl < 16; ++sl) {
    f32x4 acc = gemm_slice(afr, Wo_frag, sl, lane);
    float bias = bo[sl * 16 + lr];
#pragma unroll
    for (int r = 0; r < 4; ++r)
      out[(size_t)(r0 + hi * 4 + r) * CC + sl * 16 + lr] = acc[r] + bias;
  }
}

// ---------------------------------------------------------------------------
extern "C" void kernel_launch(void* const* d_in, const int* in_sizes, int n_in,
                              void* d_out, int out_size, void* d_ws, size_t ws_size,
                              hipStream_t stream) {
  const float* x  = (const float*)d_in[0];
  const int* batch = (const int*)d_in[1];
  const float* Wq = (const float*)d_in[2];
  const float* bq = (const float*)d_in[3];
  const float* Wk = (const float*)d_in[4];
  const float* bk = (const float*)d_in[5];
  const float* Wv = (const float*)d_in[6];
  const float* bv = (const float*)d_in[7];
  const float* Wo = (const float*)d_in[8];
  const float* bo = (const float*)d_in[9];

  char* ws = (char*)d_ws;
  unsigned short* Wfrag   = (unsigned short*)ws;             //   393,216 B
  unsigned short* Wo_frag = (unsigned short*)(ws + 393216);  //   131,072 B
  int*   seg_start = (int*)(ws + 524288);                    //     2,052 B
  float* seg_max   = (float*)(ws + 528384);                  //    32,768 B
  float* seg_sum   = (float*)(ws + 561152);                  //    32,768 B
  float* scores    = (float*)(ws + 593920);                  // 12,800,000 B
  unsigned short* v_bf = (unsigned short*)(ws + 13393920);   // 102,400,000 B

  float* out = (float*)d_out;
  float* att_mean = out + (size_t)NN * CC;

  prep_kernel<<<1024, 256, 0, stream>>>(Wq, Wk, Wv, Wo, Wfrag, Wo_frag);
  seg_bounds_kernel<<<(NN + 255) / 256, 256, 0, stream>>>(batch, seg_start, NN);
  qkv_scores_kernel<<<NN / 16, 64, 0, stream>>>(x, Wfrag, bq, bk, bv, v_bf, scores);
  seg_softmax_kernel<<<NG, 256, 0, stream>>>(scores, seg_start, seg_max, seg_sum);
  out_kernel<<<NN / 16, 64, 0, stream>>>(v_bf, scores, batch, seg_max, seg_sum,
                                         Wo_frag, bo, out, att_mean);
}